// Round 6
// baseline (269.057 us; speedup 1.0000x reference)
//
#include <hip/hip_runtime.h>
#include <hip/hip_bf16.h>
#include <stdint.h>

typedef __attribute__((ext_vector_type(8))) __bf16 bf16x8;
typedef __attribute__((ext_vector_type(4))) __bf16 bf16x4;
typedef __attribute__((ext_vector_type(2))) __bf16 bf16x2;
typedef __attribute__((ext_vector_type(4))) float f32x4;
typedef __attribute__((ext_vector_type(16))) float f32x16;
typedef __attribute__((ext_vector_type(8))) unsigned short u16x8;
typedef __attribute__((ext_vector_type(4))) unsigned int u32x4;

#define DEVI __device__ __forceinline__

DEVI void gload16(const void* g, void* l) {
  __builtin_amdgcn_global_load_lds((const __attribute__((address_space(1))) void*)g,
                                   (__attribute__((address_space(3))) void*)l, 16, 0, 0);
}

DEVI uint32_t pack2(float a, float b) {
  bf16x2 t;
  t[0] = (__bf16)a;
  t[1] = (__bf16)b;
  return __builtin_bit_cast(uint32_t, t);
}

// V swizzle for 256B rows (16x16B slots): spreads banks for key-major writes
// (d varies in bits 3-5 across a write group) and d-major reads (d low bits).
DEVI int vswz(int d) { return ((d ^ (d >> 3)) & 15) << 4; }

// ---------------- prep: weight transpose (blocks 0..2303) + x fp32->bf16 (blocks 2304..3071)
__global__ __launch_bounds__(256) void prep_k(const float* __restrict__ x,
                                              const float* __restrict__ wq,
                                              const float* __restrict__ wk,
                                              const float* __restrict__ wv,
                                              const float* __restrict__ wp,
                                              __bf16* __restrict__ xb,
                                              __bf16* __restrict__ WT) {
  __shared__ float tile[32][33];
  const int bid = blockIdx.x, tid = threadIdx.x;
  if (bid < 2304) {
    const int z = bid / 576, r = bid % 576;
    const int bx = r % 24, by = r / 24;
    const float* W = (z == 0) ? wq : (z == 1) ? wk : (z == 2) ? wv : wp;
    int n0 = bx * 32, k0 = by * 32;
    int tx = tid & 31, ty = tid >> 5;  // 32 x 8
#pragma unroll
    for (int j = 0; j < 4; ++j)
      tile[ty + 8 * j][tx] = W[(size_t)(k0 + ty + 8 * j) * 768 + n0 + tx];
    __syncthreads();
#pragma unroll
    for (int j = 0; j < 4; ++j)
      WT[(size_t)(z * 768 + n0 + ty + 8 * j) * 768 + k0 + tx] =
          (__bf16)tile[tx][ty + 8 * j];
  } else {
    const int n4 = (4096 * 768) / 4;
    int i = (bid - 2304) * 256 + tid;
    for (; i < n4; i += 768 * 256) {
      float4 v = ((const float4*)x)[i];
      bf16x4 o;
      o[0] = (__bf16)v.x; o[1] = (__bf16)v.y; o[2] = (__bf16)v.z; o[3] = (__bf16)v.w;
      ((bf16x4*)xb)[i] = o;
    }
  }
}

// ---------------- GEMM: C[M x N] = A[M x K] * B^T(rows=n)  (bf16 in, fp32 acc)
// 4-buffer pipeline, prefetch distance 2, counted vmcnt (T4), one barrier/iter.
// 1-D grid with XCD-chunked swizzle (nwg % 8 == 0 required).  [R4-verified]
template <int EPI, int BN>
__global__ __launch_bounds__(256) void gemm_k(const __bf16* __restrict__ A,
                                              const __bf16* __restrict__ B,
                                              void* __restrict__ Cout,
                                              const float* __restrict__ cosT,
                                              const float* __restrict__ sinT,
                                              int K, int lda, int ldb, int ldc,
                                              int nwg, int nxb) {
  constexpr int NF = BN / 32;       // n-frags per wave
  constexpr int LPT = 2 + BN / 64;  // gloads per thread per stage
  __shared__ __align__(16) __bf16 Al[4][128 * 32];
  __shared__ __align__(16) __bf16 Bl[4][BN * 32];
  const int tid = threadIdx.x, lane = tid & 63, w = tid >> 6;
  const int wm = w >> 1, wn = w & 1;
  const int bid = blockIdx.x;
  const int o = (bid & 7) * (nwg >> 3) + (bid >> 3);
  const int bx = o % nxb, by = o / nxb;
  const int m0 = by * 128, n0 = bx * BN;
  const int c = lane & 15, g = lane >> 4;
  f32x4 acc[4][NF] = {};

  auto stage = [&](int k0, int buf) {
#pragma unroll
    for (int i = 0; i < 2; ++i) {
      int e = (i * 256 + tid) * 8;  // elem offset in 128x32 tile
      int row = e >> 5, col = e & 31;
      gload16(A + (size_t)(m0 + row) * lda + k0 + col, (char*)&Al[buf][0] + 2 * (size_t)e);
    }
#pragma unroll
    for (int i = 0; i < BN / 64; ++i) {
      int e = (i * 256 + tid) * 8;
      int row = e >> 5, col = e & 31;
      gload16(B + (size_t)(n0 + row) * ldb + k0 + col, (char*)&Bl[buf][0] + 2 * (size_t)e);
    }
  };

  const int NIT = K / 32;
  stage(0, 0);
  stage(32, 1);
  for (int t = 0; t < NIT; ++t) {
    if (t + 2 < NIT) {
      stage((t + 2) * 32, (t + 2) & 3);
      asm volatile("s_waitcnt vmcnt(%0)" ::"i"(2 * LPT) : "memory");
    } else if (t + 1 < NIT) {
      asm volatile("s_waitcnt vmcnt(%0)" ::"i"(LPT) : "memory");
    } else {
      asm volatile("s_waitcnt vmcnt(0)" ::: "memory");
    }
    __builtin_amdgcn_s_barrier();
    const int cur = t & 3;
    bf16x8 af[4], bfr[NF];
#pragma unroll
    for (int q = 0; q < 4; ++q)
      af[q] = *(const bf16x8*)&Al[cur][(wm * 64 + q * 16 + c) * 32 + 8 * g];
#pragma unroll
    for (int q = 0; q < NF; ++q)
      bfr[q] = *(const bf16x8*)&Bl[cur][(wn * (BN / 2) + q * 16 + c) * 32 + 8 * g];
#pragma unroll
    for (int mf = 0; mf < 4; ++mf)
#pragma unroll
      for (int nf = 0; nf < NF; ++nf)
        acc[mf][nf] = __builtin_amdgcn_mfma_f32_16x16x32_bf16(af[mf], bfr[nf],
                                                              acc[mf][nf], 0, 0, 0);
  }

  if (EPI == 1) {
    __bf16* out = (__bf16*)Cout;
    const int colbase = n0 + wn * 64;       // multiple of 64 (one head-plane)
    const int plane = colbase / 768;        // 0=q,1=k,2=v
#pragma unroll
    for (int mf = 0; mf < 4; ++mf) {
#pragma unroll
      for (int r = 0; r < 4; ++r) {
        int row = m0 + wm * 64 + mf * 16 + 4 * g + r;
        float v0 = acc[mf][0][r], v1 = acc[mf][1][r], v2 = acc[mf][2][r], v3 = acc[mf][3][r];
        float y0, y1, y2, y3;
        if (plane < 2) {
          int t = row & 2047;
          float c0 = cosT[t * 32 + c],      s0 = sinT[t * 32 + c];
          float c1 = cosT[t * 32 + 16 + c], s1 = sinT[t * 32 + 16 + c];
          y0 = v0 * c0 + v2 * s0;
          y2 = v2 * c0 - v0 * s0;
          y1 = v1 * c1 + v3 * s1;
          y3 = v3 * c1 - v1 * s1;
          float ss = y0 * y0 + y1 * y1 + y2 * y2 + y3 * y3;
          ss += __shfl_xor(ss, 1); ss += __shfl_xor(ss, 2);
          ss += __shfl_xor(ss, 4); ss += __shfl_xor(ss, 8);
          float rn = rsqrtf(ss * (1.0f / 64.0f) + 1e-6f);
          y0 *= rn; y1 *= rn; y2 *= rn; y3 *= rn;
        } else {
          y0 = v0; y1 = v1; y2 = v2; y3 = v3;
        }
        size_t base = (size_t)row * ldc + colbase + c;
        out[base +  0] = (__bf16)y0;
        out[base + 16] = (__bf16)y1;
        out[base + 32] = (__bf16)y2;
        out[base + 48] = (__bf16)y3;
      }
    }
  } else {
    float* out = (float*)Cout;
#pragma unroll
    for (int mf = 0; mf < 4; ++mf)
#pragma unroll
      for (int nf = 0; nf < NF; ++nf)
#pragma unroll
        for (int r = 0; r < 4; ++r) {
          int row = m0 + wm * 64 + mf * 16 + 4 * g + r;
          out[(size_t)row * ldc + n0 + wn * (BN / 2) + nf * 16 + c] = acc[mf][nf][r];
        }
  }
}

// ---------------- flash attention (no mask), swapped-operand 32x32, KVB=128.
// 2 waves x 32 q-rows = QBLK 64; K fragments straight from global (L2-resident,
// XCD-grouped grid); V reg-staged into swizzled LDS (R2-verified path), dbuf.
__global__ __launch_bounds__(128) void attn_k(const __bf16* __restrict__ QKV,
                                              __bf16* __restrict__ Yb) {
  constexpr int TT = 2048, KVB = 128, NT = TT / KVB;
  __shared__ __align__(16) char smem[32768];
  // Vbuf[b] = smem + b*16384: [64 d][256B keys], byte = (d*256 + key*2) ^ vswz(d)
  const int tid = threadIdx.x, lane = tid & 63, w = tid >> 6;
  const int q5 = lane & 31, h = lane >> 5;
  const int bid = blockIdx.x;
  const int xcd = bid & 7, idx = bid >> 3;
  const int bh = xcd * 3 + (idx >> 5), qb = idx & 31;
  const int b = bh / 12, hd = bh % 12;
  const size_t ldq = 2304;
  const __bf16* Qg = QKV + (size_t)(b * TT) * ldq + hd * 64;
  const __bf16* Kg = QKV + (size_t)(b * TT) * ldq + 768 + hd * 64;
  const __bf16* Vg = QKV + (size_t)(b * TT) * ldq + 1536 + hd * 64;

  // Q fragment (B-operand): lane holds Q[qrow][16t + 8h .. +7]
  const int qrow = qb * 64 + w * 32 + q5;
  bf16x8 aq[4];
#pragma unroll
  for (int t = 0; t < 4; ++t)
    aq[t] = *(const bf16x8*)(Qg + (size_t)qrow * ldq + t * 16 + 8 * h);

  u16x8 vr[8];
  auto loadV = [&](int kv0) {
#pragma unroll
    for (int p = 0; p < 4; ++p) {
      int u = p * 128 + tid;
      int kp = u >> 3, d0 = (u & 7) * 8;
      const __bf16* src0 = Vg + (size_t)(kv0 + 2 * kp) * ldq + d0;
      vr[2 * p] = *(const u16x8*)src0;
      vr[2 * p + 1] = *(const u16x8*)(src0 + ldq);
    }
  };
  auto writeV = [&](int buf) {
    char* vb = smem + buf * 16384;
#pragma unroll
    for (int p = 0; p < 4; ++p) {
      int u = p * 128 + tid;
      int kp = u >> 3, d0 = (u & 7) * 8;
#pragma unroll
      for (int i = 0; i < 8; ++i) {
        int d = d0 + i;
        int byte = (d * 256 + 4 * kp) ^ vswz(d);
        uint32_t pk = (uint32_t)vr[2 * p][i] | ((uint32_t)vr[2 * p + 1][i] << 16);
        *(uint32_t*)(vb + byte) = pk;
      }
    }
  };

  f32x16 Yacc[2] = {};  // Y^T[d][q=q5], d = (r&3)+8*(r>>2)+4h+32*dh
  const float SC = 0.18033688f;  // 0.125 * log2(e)
  float m2 = -__builtin_inff(), l_run = 0.f;

  loadV(0);
  writeV(0);
  __syncthreads();

  f32x16 Sv[4];
#define SV(i) Sv[(i) >> 4][(i) & 15]

  for (int t = 0; t < NT; ++t) {
    const int cur = t & 1;
    const int kv0 = t * KVB;
    const char* Vb = smem + cur * 16384;
    if (t + 1 < NT) loadV(kv0 + KVB);  // issue next-tile V global loads early

    // ---- K fragments direct from global (A-operand: lane holds K[j*32+q5][16tt+8h..])
    bf16x8 kf[4][4];
#pragma unroll
    for (int j = 0; j < 4; ++j)
#pragma unroll
      for (int tt = 0; tt < 4; ++tt)
        kf[j][tt] = *(const bf16x8*)(Kg + (size_t)(kv0 + j * 32 + q5) * ldq + tt * 16 + 8 * h);

    // ---- S^T = mfma(A=K, B=Q): lane owns q=q5; 64 scores
#pragma unroll
    for (int j = 0; j < 4; ++j) {
      f32x16 S = {};
#pragma unroll
      for (int tt = 0; tt < 4; ++tt)
        S = __builtin_amdgcn_mfma_f32_32x32x16_bf16(kf[j][tt], aq[tt], S, 0, 0, 0);
      Sv[j] = S;
    }

    // ---- online softmax (exp2 domain); 4-chain trees, defer-max rescale
    float m0 = SV(0), m1 = SV(1), m2c = SV(2), m3 = SV(3);
#pragma unroll
    for (int i = 4; i < 64; i += 4) {
      m0 = fmaxf(m0, SV(i));       m1 = fmaxf(m1, SV(i + 1));
      m2c = fmaxf(m2c, SV(i + 2)); m3 = fmaxf(m3, SV(i + 3));
    }
    float mx = fmaxf(fmaxf(m0, m1), fmaxf(m2c, m3));
    mx = fmaxf(mx, __shfl_xor(mx, 32));
    mx *= SC;
    if (!__all(mx <= m2 + 8.0f)) {  // defer rescale while P <= 2^8
      float mn = fmaxf(m2, mx);
      float corr = __builtin_exp2f(m2 - mn);
      l_run *= corr;
#pragma unroll
      for (int dh = 0; dh < 2; ++dh)
#pragma unroll
        for (int r = 0; r < 16; ++r) Yacc[dh][r] *= corr;
      m2 = mn;
    }
    float rs0 = 0.f, rs1 = 0.f, rs2 = 0.f, rs3 = 0.f;
#pragma unroll
    for (int i = 0; i < 64; i += 4) {
      float e0 = __builtin_exp2f(fmaf(SV(i), SC, -m2));
      float e1 = __builtin_exp2f(fmaf(SV(i + 1), SC, -m2));
      float e2 = __builtin_exp2f(fmaf(SV(i + 2), SC, -m2));
      float e3 = __builtin_exp2f(fmaf(SV(i + 3), SC, -m2));
      SV(i) = e0; SV(i + 1) = e1; SV(i + 2) = e2; SV(i + 3) = e3;
      rs0 += e0; rs1 += e1; rs2 += e2; rs3 += e3;
    }
    float rs = (rs0 + rs1) + (rs2 + rs3);
    rs += __shfl_xor(rs, 32);
    l_run += rs;

    // ---- Y^T += mfma(A=V^T from swizzled LDS, B=P^T) per 16-key sub-tile
#pragma unroll
    for (int j = 0; j < 4; ++j) {
#pragma unroll
      for (int s = 0; s < 2; ++s) {
        int e0 = j * 16 + s * 8;
        uint32_t pk01 = pack2(SV(e0 + 0), SV(e0 + 1));
        uint32_t pk23 = pack2(SV(e0 + 2), SV(e0 + 3));
        uint32_t pk45 = pack2(SV(e0 + 4), SV(e0 + 5));
        uint32_t pk67 = pack2(SV(e0 + 6), SV(e0 + 7));
        uint32_t fa = (uint32_t)__shfl_xor((int)(h ? pk01 : pk45), 32);
        uint32_t fb = (uint32_t)__shfl_xor((int)(h ? pk23 : pk67), 32);
        u32x4 pw;
        pw[0] = h ? fa : pk01;
        pw[1] = h ? fb : pk23;
        pw[2] = h ? pk45 : fa;
        pw[3] = h ? pk67 : fb;
        bf16x8 pfrag = __builtin_bit_cast(bf16x8, pw);
        int keyb = j * 64 + s * 32 + 16 * h;  // (32j+16s+8h) keys * 2B
#pragma unroll
        for (int dh = 0; dh < 2; ++dh) {
          int d = dh * 32 + q5;
          int byte = (d * 256 + keyb) ^ vswz(d);
          bf16x8 vf = *(const bf16x8*)(Vb + byte);
          Yacc[dh] = __builtin_amdgcn_mfma_f32_32x32x16_bf16(vf, pfrag, Yacc[dh], 0, 0, 0);
        }
      }
    }
    if (t + 1 < NT) writeV(cur ^ 1);  // commit next tile's V to other buffer
    __syncthreads();
  }
#undef SV

  // ---- epilogue: scale by 1/l, transpose via LDS (reuse smem), coalesced stores
  float rl = __builtin_amdgcn_rcpf(l_run);
  char* yb = smem + w * (32 * 144);  // per-wave [32 q][72 bf16] region (144B rows)
#pragma unroll
  for (int dh = 0; dh < 2; ++dh)
#pragma unroll
    for (int a = 0; a < 4; ++a) {
      bf16x4 pkv;
#pragma unroll
      for (int i = 0; i < 4; ++i) pkv[i] = (__bf16)(Yacc[dh][a * 4 + i] * rl);
      int d0 = a * 8 + 4 * h + 32 * dh;
      *(bf16x4*)(yb + q5 * 144 + d0 * 2) = pkv;
    }
  __syncthreads();
  __bf16* Yrow = Yb + (size_t)(b * TT + qb * 64 + w * 32) * 768 + hd * 64;
#pragma unroll
  for (int k = 0; k < 4; ++k) {
    int chunk = k * 64 + lane;
    int qr = chunk >> 3, sr = chunk & 7;
    bf16x8 vv = *(const bf16x8*)(yb + qr * 144 + sr * 16);
    *(bf16x8*)(Yrow + (size_t)qr * 768 + sr * 8) = vv;
  }
}

extern "C" void kernel_launch(void* const* d_in, const int* in_sizes, int n_in,
                              void* d_out, int out_size, void* d_ws, size_t ws_size,
                              hipStream_t stream) {
  const float* x = (const float*)d_in[0];
  const float* cosT = (const float*)d_in[1];
  const float* sinT = (const float*)d_in[2];
  const float* wq = (const float*)d_in[3];
  const float* wk = (const float*)d_in[4];
  const float* wv = (const float*)d_in[5];
  const float* wp = (const float*)d_in[6];

  char* ws = (char*)d_ws;
  __bf16* xb   = (__bf16*)(ws);                 //  6,291,456 B  (4096x768 bf16)
  __bf16* WT   = (__bf16*)(ws + 6291456);       //  4,718,592 B  (3072x768 bf16)
  __bf16* QKVb = (__bf16*)(ws + 11010048);      // 18,874,368 B  (4096x2304 bf16)
  __bf16* Yb   = (__bf16*)(ws + 29884416);      //  6,291,456 B  (4096x768 bf16)

  prep_k<<<3072, 256, 0, stream>>>(x, wq, wk, wv, wp, xb, WT);
  // fused QKV gemm: M=4096, N=2304, K=768; 576 blocks (72/XCD)
  gemm_k<1, 128><<<576, 256, 0, stream>>>(xb, WT, (void*)QKVb, cosT, sinT,
                                          768, 768, 768, 2304, 576, 18);
  attn_k<<<768, 128, 0, stream>>>(QKVb, Yb);
  // proj gemm: M=4096, N=768, K=768, 128x64 tiles -> 384 blocks (48/XCD)
  gemm_k<0, 64><<<384, 256, 0, stream>>>(Yb, WT + (size_t)2304 * 768, d_out,
                                         nullptr, nullptr, 768, 768, 768, 768, 384, 12);
}

// Round 7
// 200.712 us; speedup vs baseline: 1.3405x; 1.3405x over previous
//
#include <hip/hip_runtime.h>
#include <hip/hip_bf16.h>
#include <stdint.h>

typedef __attribute__((ext_vector_type(8))) __bf16 bf16x8;
typedef __attribute__((ext_vector_type(4))) __bf16 bf16x4;
typedef __attribute__((ext_vector_type(2))) __bf16 bf16x2;
typedef __attribute__((ext_vector_type(4))) float f32x4;
typedef __attribute__((ext_vector_type(16))) float f32x16;
typedef __attribute__((ext_vector_type(8))) unsigned short u16x8;
typedef __attribute__((ext_vector_type(4))) unsigned int u32x4;

#define DEVI __device__ __forceinline__

DEVI void gload16(const void* g, void* l) {
  __builtin_amdgcn_global_load_lds((const __attribute__((address_space(1))) void*)g,
                                   (__attribute__((address_space(3))) void*)l, 16, 0, 0);
}

DEVI uint32_t pack2(float a, float b) {
  bf16x2 t;
  t[0] = (__bf16)a;
  t[1] = (__bf16)b;
  return __builtin_bit_cast(uint32_t, t);
}

// V swizzle for 256B rows (16x16B slots): spreads banks for both key-major
// writes and d-major reads.  [verified R3 bench: conflicts 7.15M -> 1.65M]
DEVI int vswz(int d) { return ((d ^ (d >> 3)) & 15) << 4; }

// ---------------- prep: weight transpose (blocks 0..2303) + x fp32->bf16 (2304..3071)
__global__ __launch_bounds__(256) void prep_k(const float* __restrict__ x,
                                              const float* __restrict__ wq,
                                              const float* __restrict__ wk,
                                              const float* __restrict__ wv,
                                              const float* __restrict__ wp,
                                              __bf16* __restrict__ xb,
                                              __bf16* __restrict__ WT) {
  __shared__ float tile[32][33];
  const int bid = blockIdx.x, tid = threadIdx.x;
  if (bid < 2304) {
    const int z = bid / 576, r = bid % 576;
    const int bx = r % 24, by = r / 24;
    const float* W = (z == 0) ? wq : (z == 1) ? wk : (z == 2) ? wv : wp;
    int n0 = bx * 32, k0 = by * 32;
    int tx = tid & 31, ty = tid >> 5;  // 32 x 8
#pragma unroll
    for (int j = 0; j < 4; ++j)
      tile[ty + 8 * j][tx] = W[(size_t)(k0 + ty + 8 * j) * 768 + n0 + tx];
    __syncthreads();
#pragma unroll
    for (int j = 0; j < 4; ++j)
      WT[(size_t)(z * 768 + n0 + ty + 8 * j) * 768 + k0 + tx] =
          (__bf16)tile[tx][ty + 8 * j];
  } else {
    const int n4 = (4096 * 768) / 4;
    int i = (bid - 2304) * 256 + tid;
    for (; i < n4; i += 768 * 256) {
      float4 v = ((const float4*)x)[i];
      bf16x4 o;
      o[0] = (__bf16)v.x; o[1] = (__bf16)v.y; o[2] = (__bf16)v.z; o[3] = (__bf16)v.w;
      ((bf16x4*)xb)[i] = o;
    }
  }
}

// ---------------- GEMM: C[M x N] = A[M x K] * B^T(rows=n)  (bf16 in, fp32 acc)
// 4-buffer pipeline, prefetch distance 2, counted vmcnt, one barrier/iter.
// 1-D grid with XCD-chunked swizzle (nwg % 8 == 0).  [verified R4/R6]
template <int EPI, int BN>
__global__ __launch_bounds__(256) void gemm_k(const __bf16* __restrict__ A,
                                              const __bf16* __restrict__ B,
                                              void* __restrict__ Cout,
                                              const float* __restrict__ cosT,
                                              const float* __restrict__ sinT,
                                              int K, int lda, int ldb, int ldc,
                                              int nwg, int nxb) {
  constexpr int NF = BN / 32;       // n-frags per wave
  constexpr int LPT = 2 + BN / 64;  // gloads per thread per stage
  __shared__ __align__(16) __bf16 Al[4][128 * 32];
  __shared__ __align__(16) __bf16 Bl[4][BN * 32];
  const int tid = threadIdx.x, lane = tid & 63, w = tid >> 6;
  const int wm = w >> 1, wn = w & 1;
  const int bid = blockIdx.x;
  const int o = (bid & 7) * (nwg >> 3) + (bid >> 3);
  const int bx = o % nxb, by = o / nxb;
  const int m0 = by * 128, n0 = bx * BN;
  const int c = lane & 15, g = lane >> 4;
  f32x4 acc[4][NF] = {};

  auto stage = [&](int k0, int buf) {
#pragma unroll
    for (int i = 0; i < 2; ++i) {
      int e = (i * 256 + tid) * 8;  // elem offset in 128x32 tile
      int row = e >> 5, col = e & 31;
      gload16(A + (size_t)(m0 + row) * lda + k0 + col, (char*)&Al[buf][0] + 2 * (size_t)e);
    }
#pragma unroll
    for (int i = 0; i < BN / 64; ++i) {
      int e = (i * 256 + tid) * 8;
      int row = e >> 5, col = e & 31;
      gload16(B + (size_t)(n0 + row) * ldb + k0 + col, (char*)&Bl[buf][0] + 2 * (size_t)e);
    }
  };

  const int NIT = K / 32;
  stage(0, 0);
  stage(32, 1);
  for (int t = 0; t < NIT; ++t) {
    if (t + 2 < NIT) {
      stage((t + 2) * 32, (t + 2) & 3);
      asm volatile("s_waitcnt vmcnt(%0)" ::"i"(2 * LPT) : "memory");
    } else if (t + 1 < NIT) {
      asm volatile("s_waitcnt vmcnt(%0)" ::"i"(LPT) : "memory");
    } else {
      asm volatile("s_waitcnt vmcnt(0)" ::: "memory");
    }
    __builtin_amdgcn_s_barrier();
    const int cur = t & 3;
    bf16x8 af[4], bfr[NF];
#pragma unroll
    for (int q = 0; q < 4; ++q)
      af[q] = *(const bf16x8*)&Al[cur][(wm * 64 + q * 16 + c) * 32 + 8 * g];
#pragma unroll
    for (int q = 0; q < NF; ++q)
      bfr[q] = *(const bf16x8*)&Bl[cur][(wn * (BN / 2) + q * 16 + c) * 32 + 8 * g];
#pragma unroll
    for (int mf = 0; mf < 4; ++mf)
#pragma unroll
      for (int nf = 0; nf < NF; ++nf)
        acc[mf][nf] = __builtin_amdgcn_mfma_f32_16x16x32_bf16(af[mf], bfr[nf],
                                                              acc[mf][nf], 0, 0, 0);
  }

  if (EPI == 1) {
    __bf16* out = (__bf16*)Cout;
    const int colbase = n0 + wn * 64;       // multiple of 64 (one head-plane)
    const int plane = colbase / 768;        // 0=q,1=k,2=v
#pragma unroll
    for (int mf = 0; mf < 4; ++mf) {
#pragma unroll
      for (int r = 0; r < 4; ++r) {
        int row = m0 + wm * 64 + mf * 16 + 4 * g + r;
        float v0 = acc[mf][0][r], v1 = acc[mf][1][r], v2 = acc[mf][2][r], v3 = acc[mf][3][r];
        float y0, y1, y2, y3;
        if (plane < 2) {
          int t = row & 2047;
          float c0 = cosT[t * 32 + c],      s0 = sinT[t * 32 + c];
          float c1 = cosT[t * 32 + 16 + c], s1 = sinT[t * 32 + 16 + c];
          y0 = v0 * c0 + v2 * s0;
          y2 = v2 * c0 - v0 * s0;
          y1 = v1 * c1 + v3 * s1;
          y3 = v3 * c1 - v1 * s1;
          float ss = y0 * y0 + y1 * y1 + y2 * y2 + y3 * y3;
          ss += __shfl_xor(ss, 1); ss += __shfl_xor(ss, 2);
          ss += __shfl_xor(ss, 4); ss += __shfl_xor(ss, 8);
          float rn = rsqrtf(ss * (1.0f / 64.0f) + 1e-6f);
          y0 *= rn; y1 *= rn; y2 *= rn; y3 *= rn;
        } else {
          y0 = v0; y1 = v1; y2 = v2; y3 = v3;
        }
        size_t base = (size_t)row * ldc + colbase + c;
        out[base +  0] = (__bf16)y0;
        out[base + 16] = (__bf16)y1;
        out[base + 32] = (__bf16)y2;
        out[base + 48] = (__bf16)y3;
      }
    }
  } else {
    float* out = (float*)Cout;
#pragma unroll
    for (int mf = 0; mf < 4; ++mf)
#pragma unroll
      for (int nf = 0; nf < NF; ++nf)
#pragma unroll
        for (int r = 0; r < 4; ++r) {
          int row = m0 + wm * 64 + mf * 16 + 4 * g + r;
          out[(size_t)row * ldc + n0 + wn * (BN / 2) + nf * 16 + c] = acc[mf][nf][r];
        }
  }
}

// ---------------- flash attention (no mask), swapped-operand 32x32 structure.
// [= Round-3's verified 58.8 us kernel + XCD-grouped grid + exp2 softmax]
// 4 waves x 32 q-rows = QBLK 128; KVBLK=128; K via swizzled global_load_lds dbuf;
// V reg-staged into swizzled LDS dbuf; prefetch-before-compute; 1 barrier/tile.
// 1-D grid 384: all 16 qb-blocks of a head on one XCD (3 heads/XCD, L2-resident).
__global__ __launch_bounds__(256, 2) void attn_k(const __bf16* __restrict__ QKV,
                                                 __bf16* __restrict__ Yb) {
  constexpr int TT = 2048, KVB = 128, NT = TT / KVB;
  __shared__ __align__(16) char smem[65536];
  // Kbuf[b] = smem + b*16384: [128 keys][128B], 16B chunk s holds logical chunk s^(row&7)
  // Vbuf[b] = smem + 32768 + b*16384: [64 d][256B keys], byte = (d*256 + key*2) ^ vswz(d)
  const int tid = threadIdx.x, lane = tid & 63, w = tid >> 6;
  const int q5 = lane & 31, h = lane >> 5;
  const int bid = blockIdx.x;
  const int xcd = bid & 7, idx = bid >> 3;     // 48 blocks per XCD
  const int bh = xcd * 3 + (idx >> 4), qb = idx & 15;
  const int b = bh / 12, hd = bh % 12;
  const size_t ldq = 2304;
  const __bf16* Qg = QKV + (size_t)(b * TT) * ldq + hd * 64;
  const __bf16* Kg = QKV + (size_t)(b * TT) * ldq + 768 + hd * 64;
  const __bf16* Vg = QKV + (size_t)(b * TT) * ldq + 1536 + hd * 64;

  // Q fragment (B-operand): lane holds Q[qrow][16t + 8h .. +7]
  const int qrow = qb * 128 + w * 32 + q5;
  bf16x8 aq[4];
#pragma unroll
  for (int t = 0; t < 4; ++t)
    aq[t] = *(const bf16x8*)(Qg + (size_t)qrow * ldq + t * 16 + 8 * h);

  u16x8 vr[4];
  auto stageK = [&](int kv0, int buf) {
#pragma unroll
    for (int p = 0; p < 4; ++p) {
      int cid = p * 256 + tid;
      int row = cid >> 3, s = cid & 7;
      int srccol = 8 * (s ^ (row & 7));
      gload16(Kg + (size_t)(kv0 + row) * ldq + srccol,
              smem + buf * 16384 + row * 128 + 16 * s);
    }
  };
  auto loadV = [&](int kv0) {
#pragma unroll
    for (int p = 0; p < 2; ++p) {
      int u = p * 256 + tid;
      int kp = u >> 3, d0 = (u & 7) * 8;
      const __bf16* src0 = Vg + (size_t)(kv0 + 2 * kp) * ldq + d0;
      vr[2 * p] = *(const u16x8*)src0;
      vr[2 * p + 1] = *(const u16x8*)(src0 + ldq);
    }
  };
  auto writeV = [&](int buf) {
    char* vb = smem + 32768 + buf * 16384;
#pragma unroll
    for (int p = 0; p < 2; ++p) {
      int u = p * 256 + tid;
      int kp = u >> 3, d0 = (u & 7) * 8;
#pragma unroll
      for (int i = 0; i < 8; ++i) {
        int d = d0 + i;
        int byte = (d * 256 + 4 * kp) ^ vswz(d);
        uint32_t pk = (uint32_t)vr[2 * p][i] | ((uint32_t)vr[2 * p + 1][i] << 16);
        *(uint32_t*)(vb + byte) = pk;
      }
    }
  };

  f32x16 Yacc[2] = {};  // Y^T[d][q=q5], d = (r&3)+8*(r>>2)+4h+32*dh
  const float SC = 0.18033688f;  // 0.125 * log2(e)  (softmax in exp2 domain)
  float m2 = -__builtin_inff(), l_run = 0.f;

  stageK(0, 0);
  loadV(0);
  writeV(0);
  __syncthreads();

  f32x16 Sv[4];
#define SV(i) Sv[(i) >> 4][(i) & 15]

  for (int t = 0; t < NT; ++t) {
    const int cur = t & 1;
    const char* Kb = smem + cur * 16384;
    const char* Vb = smem + 32768 + cur * 16384;
    if (t + 1 < NT) {
      stageK((t + 1) * KVB, cur ^ 1);
      loadV((t + 1) * KVB);
    }

    // ---- S^T = mfma(A=K, B=Q): lane owns q=q5; 64 scores
#pragma unroll
    for (int j = 0; j < 4; ++j) {
      f32x16 S = {};
#pragma unroll
      for (int tt = 0; tt < 4; ++tt) {
        int row = j * 32 + q5;
        int chunk = (2 * tt + h) ^ (q5 & 7);
        bf16x8 kf = *(const bf16x8*)(Kb + row * 128 + 16 * chunk);
        S = __builtin_amdgcn_mfma_f32_32x32x16_bf16(kf, aq[tt], S, 0, 0, 0);
      }
      Sv[j] = S;
    }

    // ---- online softmax (exp2 domain); 4-chain trees, defer-max rescale
    float m0 = SV(0), m1 = SV(1), m2c = SV(2), m3 = SV(3);
#pragma unroll
    for (int i = 4; i < 64; i += 4) {
      m0 = fmaxf(m0, SV(i));       m1 = fmaxf(m1, SV(i + 1));
      m2c = fmaxf(m2c, SV(i + 2)); m3 = fmaxf(m3, SV(i + 3));
    }
    float mx = fmaxf(fmaxf(m0, m1), fmaxf(m2c, m3));
    mx = fmaxf(mx, __shfl_xor(mx, 32));
    mx *= SC;
    if (!__all(mx <= m2 + 8.0f)) {  // defer rescale while P <= 2^8
      float mn = fmaxf(m2, mx);
      float corr = __builtin_exp2f(m2 - mn);
      l_run *= corr;
#pragma unroll
      for (int dh = 0; dh < 2; ++dh)
#pragma unroll
        for (int r = 0; r < 16; ++r) Yacc[dh][r] *= corr;
      m2 = mn;
    }
    float rs0 = 0.f, rs1 = 0.f, rs2 = 0.f, rs3 = 0.f;
#pragma unroll
    for (int i = 0; i < 64; i += 4) {
      float e0 = __builtin_exp2f(fmaf(SV(i), SC, -m2));
      float e1 = __builtin_exp2f(fmaf(SV(i + 1), SC, -m2));
      float e2 = __builtin_exp2f(fmaf(SV(i + 2), SC, -m2));
      float e3 = __builtin_exp2f(fmaf(SV(i + 3), SC, -m2));
      SV(i) = e0; SV(i + 1) = e1; SV(i + 2) = e2; SV(i + 3) = e3;
      rs0 += e0; rs1 += e1; rs2 += e2; rs3 += e3;
    }
    float rs = (rs0 + rs1) + (rs2 + rs3);
    rs += __shfl_xor(rs, 32);
    l_run += rs;

    // ---- Y^T += mfma(A=V^T from swizzled LDS, B=P^T) per 16-key sub-tile
#pragma unroll
    for (int j = 0; j < 4; ++j) {
#pragma unroll
      for (int s = 0; s < 2; ++s) {
        int e0 = j * 16 + s * 8;
        uint32_t pk01 = pack2(SV(e0 + 0), SV(e0 + 1));
        uint32_t pk23 = pack2(SV(e0 + 2), SV(e0 + 3));
        uint32_t pk45 = pack2(SV(e0 + 4), SV(e0 + 5));
        uint32_t pk67 = pack2(SV(e0 + 6), SV(e0 + 7));
        uint32_t fa = (uint32_t)__shfl_xor((int)(h ? pk01 : pk45), 32);
        uint32_t fb = (uint32_t)__shfl_xor((int)(h ? pk23 : pk67), 32);
        u32x4 pw;
        pw[0] = h ? fa : pk01;
        pw[1] = h ? fb : pk23;
        pw[2] = h ? pk45 : fa;
        pw[3] = h ? pk67 : fb;
        bf16x8 pfrag = __builtin_bit_cast(bf16x8, pw);
        int keyb = j * 64 + s * 32 + 16 * h;  // (32j+16s+8h) keys * 2B
#pragma unroll
        for (int dh = 0; dh < 2; ++dh) {
          int d = dh * 32 + q5;
          int byte = (d * 256 + keyb) ^ vswz(d);
          bf16x8 vf = *(const bf16x8*)(Vb + byte);
          Yacc[dh] = __builtin_amdgcn_mfma_f32_32x32x16_bf16(vf, pfrag, Yacc[dh], 0, 0, 0);
        }
      }
    }
    if (t + 1 < NT) writeV(cur ^ 1);
    __syncthreads();
  }
#undef SV

  // ---- epilogue: scale by 1/l, transpose via LDS (reuse smem), coalesced stores
  float rl = __builtin_amdgcn_rcpf(l_run);
  char* yb = smem + w * (32 * 144);  // per-wave [32 q][72 bf16] region (144B rows)
#pragma unroll
  for (int dh = 0; dh < 2; ++dh)
#pragma unroll
    for (int a = 0; a < 4; ++a) {
      bf16x4 pkv;
#pragma unroll
      for (int i = 0; i < 4; ++i) pkv[i] = (__bf16)(Yacc[dh][a * 4 + i] * rl);
      int d0 = a * 8 + 4 * h + 32 * dh;
      *(bf16x4*)(yb + q5 * 144 + d0 * 2) = pkv;
    }
  __bf16* Yrow = Yb + (size_t)(b * TT + qb * 128 + w * 32) * 768 + hd * 64;
#pragma unroll
  for (int k = 0; k < 4; ++k) {
    int chunk = k * 64 + lane;
    int qr = chunk >> 3, sr = chunk & 7;
    bf16x8 vv = *(const bf16x8*)(yb + qr * 144 + sr * 16);
    *(bf16x8*)(Yrow + (size_t)qr * 768 + sr * 8) = vv;
  }
}

extern "C" void kernel_launch(void* const* d_in, const int* in_sizes, int n_in,
                              void* d_out, int out_size, void* d_ws, size_t ws_size,
                              hipStream_t stream) {
  const float* x = (const float*)d_in[0];
  const float* cosT = (const float*)d_in[1];
  const float* sinT = (const float*)d_in[2];
  const float* wq = (const float*)d_in[3];
  const float* wk = (const float*)d_in[4];
  const float* wv = (const float*)d_in[5];
  const float* wp = (const float*)d_in[6];

  char* ws = (char*)d_ws;
  __bf16* xb   = (__bf16*)(ws);                 //  6,291,456 B  (4096x768 bf16)
  __bf16* WT   = (__bf16*)(ws + 6291456);       //  4,718,592 B  (3072x768 bf16)
  __bf16* QKVb = (__bf16*)(ws + 11010048);      // 18,874,368 B  (4096x2304 bf16)
  __bf16* Yb   = (__bf16*)(ws + 29884416);      //  6,291,456 B  (4096x768 bf16)

  prep_k<<<3072, 256, 0, stream>>>(x, wq, wk, wv, wp, xb, WT);
  // fused QKV gemm: M=4096, N=2304, K=768; 576 blocks (72/XCD)
  gemm_k<1, 128><<<576, 256, 0, stream>>>(xb, WT, (void*)QKVb, cosT, sinT,
                                          768, 768, 768, 2304, 576, 18);
  // attn: 384 blocks (48/XCD: 3 heads x 16 qb), 256 threads
  attn_k<<<384, 256, 0, stream>>>(QKVb, Yb);
  // proj gemm: M=4096, N=768, K=768, 128x64 tiles -> 384 blocks (48/XCD)
  gemm_k<0, 64><<<384, 256, 0, stream>>>(Yb, WT + (size_t)2304 * 768, d_out,
                                         nullptr, nullptr, 768, 768, 768, 768, 384, 12);
}

// Round 8
// 190.737 us; speedup vs baseline: 1.4106x; 1.0523x over previous
//
#include <hip/hip_runtime.h>
#include <hip/hip_bf16.h>
#include <stdint.h>

typedef __attribute__((ext_vector_type(8))) __bf16 bf16x8;
typedef __attribute__((ext_vector_type(4))) __bf16 bf16x4;
typedef __attribute__((ext_vector_type(2))) __bf16 bf16x2;
typedef __attribute__((ext_vector_type(4))) float f32x4;
typedef __attribute__((ext_vector_type(16))) float f32x16;
typedef __attribute__((ext_vector_type(4))) unsigned int u32x4;

#define DEVI __device__ __forceinline__

DEVI void gload16(const void* g, void* l) {
  __builtin_amdgcn_global_load_lds((const __attribute__((address_space(1))) void*)g,
                                   (__attribute__((address_space(3))) void*)l, 16, 0, 0);
}

DEVI uint32_t pack2(float a, float b) {
  bf16x2 t;
  t[0] = (__bf16)a;
  t[1] = (__bf16)b;
  return __builtin_bit_cast(uint32_t, t);
}

// ---------------- prep: weight transpose (blocks 0..2303) + x fp32->bf16 (2304..3071)
__global__ __launch_bounds__(256) void prep_k(const float* __restrict__ x,
                                              const float* __restrict__ wq,
                                              const float* __restrict__ wk,
                                              const float* __restrict__ wv,
                                              const float* __restrict__ wp,
                                              __bf16* __restrict__ xb,
                                              __bf16* __restrict__ WT) {
  __shared__ float tile[32][33];
  const int bid = blockIdx.x, tid = threadIdx.x;
  if (bid < 2304) {
    const int z = bid / 576, r = bid % 576;
    const int bx = r % 24, by = r / 24;
    const float* W = (z == 0) ? wq : (z == 1) ? wk : (z == 2) ? wv : wp;
    int n0 = bx * 32, k0 = by * 32;
    int tx = tid & 31, ty = tid >> 5;  // 32 x 8
#pragma unroll
    for (int j = 0; j < 4; ++j)
      tile[ty + 8 * j][tx] = W[(size_t)(k0 + ty + 8 * j) * 768 + n0 + tx];
    __syncthreads();
#pragma unroll
    for (int j = 0; j < 4; ++j)
      WT[(size_t)(z * 768 + n0 + ty + 8 * j) * 768 + k0 + tx] =
          (__bf16)tile[tx][ty + 8 * j];
  } else {
    const int n4 = (4096 * 768) / 4;
    int i = (bid - 2304) * 256 + tid;
    for (; i < n4; i += 768 * 256) {
      float4 v = ((const float4*)x)[i];
      bf16x4 o;
      o[0] = (__bf16)v.x; o[1] = (__bf16)v.y; o[2] = (__bf16)v.z; o[3] = (__bf16)v.w;
      ((bf16x4*)xb)[i] = o;
    }
  }
}

// ---------------- GEMM: C[M x N] = A[M x K] * B^T(rows=n)  (bf16 in, fp32 acc)
// 4-buffer pipeline, prefetch distance 2, counted vmcnt, one barrier/iter. [R4/R6/R7-verified]
// EPI=1 (QKV): Q,K planes -> rope+rms, bf16 out at ldc=1536; V plane -> transposed
//              write to Vt[(b*12+h)*64 + d][t] (key-contiguous).
// EPI=0: plain fp32 out.
template <int EPI, int BN>
__global__ __launch_bounds__(256) void gemm_k(const __bf16* __restrict__ A,
                                              const __bf16* __restrict__ B,
                                              void* __restrict__ Cout,
                                              __bf16* __restrict__ Vt,
                                              const float* __restrict__ cosT,
                                              const float* __restrict__ sinT,
                                              int K, int lda, int ldb, int ldc,
                                              int nwg, int nxb) {
  constexpr int NF = BN / 32;       // n-frags per wave
  constexpr int LPT = 2 + BN / 64;  // gloads per thread per stage
  __shared__ __align__(16) __bf16 Al[4][128 * 32];
  __shared__ __align__(16) __bf16 Bl[4][BN * 32];
  const int tid = threadIdx.x, lane = tid & 63, w = tid >> 6;
  const int wm = w >> 1, wn = w & 1;
  const int bid = blockIdx.x;
  const int o = (bid & 7) * (nwg >> 3) + (bid >> 3);
  const int bx = o % nxb, by = o / nxb;
  const int m0 = by * 128, n0 = bx * BN;
  const int c = lane & 15, g = lane >> 4;
  f32x4 acc[4][NF] = {};

  auto stage = [&](int k0, int buf) {
#pragma unroll
    for (int i = 0; i < 2; ++i) {
      int e = (i * 256 + tid) * 8;  // elem offset in 128x32 tile
      int row = e >> 5, col = e & 31;
      gload16(A + (size_t)(m0 + row) * lda + k0 + col, (char*)&Al[buf][0] + 2 * (size_t)e);
    }
#pragma unroll
    for (int i = 0; i < BN / 64; ++i) {
      int e = (i * 256 + tid) * 8;
      int row = e >> 5, col = e & 31;
      gload16(B + (size_t)(n0 + row) * ldb + k0 + col, (char*)&Bl[buf][0] + 2 * (size_t)e);
    }
  };

  const int NIT = K / 32;
  stage(0, 0);
  stage(32, 1);
  for (int t = 0; t < NIT; ++t) {
    if (t + 2 < NIT) {
      stage((t + 2) * 32, (t + 2) & 3);
      asm volatile("s_waitcnt vmcnt(%0)" ::"i"(2 * LPT) : "memory");
    } else if (t + 1 < NIT) {
      asm volatile("s_waitcnt vmcnt(%0)" ::"i"(LPT) : "memory");
    } else {
      asm volatile("s_waitcnt vmcnt(0)" ::: "memory");
    }
    __builtin_amdgcn_s_barrier();
    const int cur = t & 3;
    bf16x8 af[4], bfr[NF];
#pragma unroll
    for (int q = 0; q < 4; ++q)
      af[q] = *(const bf16x8*)&Al[cur][(wm * 64 + q * 16 + c) * 32 + 8 * g];
#pragma unroll
    for (int q = 0; q < NF; ++q)
      bfr[q] = *(const bf16x8*)&Bl[cur][(wn * (BN / 2) + q * 16 + c) * 32 + 8 * g];
#pragma unroll
    for (int mf = 0; mf < 4; ++mf)
#pragma unroll
      for (int nf = 0; nf < NF; ++nf)
        acc[mf][nf] = __builtin_amdgcn_mfma_f32_16x16x32_bf16(af[mf], bfr[nf],
                                                              acc[mf][nf], 0, 0, 0);
  }

  if (EPI == 1) {
    const int colbase = n0 + wn * 64;       // multiple of 64 (one head-plane)
    const int plane = colbase / 768;        // 0=q,1=k,2=v
    if (plane == 2) {
      // V: write transposed. lane holds 4 consecutive keys (rows) at fixed d.
      const int hd = (colbase - 1536) >> 6;
#pragma unroll
      for (int mf = 0; mf < 4; ++mf)
#pragma unroll
        for (int nf = 0; nf < 4; ++nf) {
          bf16x4 pk;
#pragma unroll
          for (int r = 0; r < 4; ++r) pk[r] = (__bf16)acc[mf][nf][r];
          int row = m0 + wm * 64 + mf * 16 + 4 * g;
          int bb = row >> 11, tloc = row & 2047;
          int d = nf * 16 + c;
          *(bf16x4*)(Vt + ((size_t)(bb * 12 + hd) * 64 + d) * 2048 + tloc) = pk;
        }
    } else {
      __bf16* out = (__bf16*)Cout;
#pragma unroll
      for (int mf = 0; mf < 4; ++mf) {
#pragma unroll
        for (int r = 0; r < 4; ++r) {
          int row = m0 + wm * 64 + mf * 16 + 4 * g + r;
          float v0 = acc[mf][0][r], v1 = acc[mf][1][r], v2 = acc[mf][2][r], v3 = acc[mf][3][r];
          int t = row & 2047;
          float c0 = cosT[t * 32 + c],      s0 = sinT[t * 32 + c];
          float c1 = cosT[t * 32 + 16 + c], s1 = sinT[t * 32 + 16 + c];
          float y0 = v0 * c0 + v2 * s0;
          float y2 = v2 * c0 - v0 * s0;
          float y1 = v1 * c1 + v3 * s1;
          float y3 = v3 * c1 - v1 * s1;
          float ss = y0 * y0 + y1 * y1 + y2 * y2 + y3 * y3;
          ss += __shfl_xor(ss, 1); ss += __shfl_xor(ss, 2);
          ss += __shfl_xor(ss, 4); ss += __shfl_xor(ss, 8);
          float rn = rsqrtf(ss * (1.0f / 64.0f) + 1e-6f);
          y0 *= rn; y1 *= rn; y2 *= rn; y3 *= rn;
          size_t base = (size_t)row * ldc + colbase + c;
          out[base +  0] = (__bf16)y0;
          out[base + 16] = (__bf16)y1;
          out[base + 32] = (__bf16)y2;
          out[base + 48] = (__bf16)y3;
        }
      }
    }
  } else {
    float* out = (float*)Cout;
#pragma unroll
    for (int mf = 0; mf < 4; ++mf)
#pragma unroll
      for (int nf = 0; nf < NF; ++nf)
#pragma unroll
        for (int r = 0; r < 4; ++r) {
          int row = m0 + wm * 64 + mf * 16 + 4 * g + r;
          out[(size_t)row * ldc + n0 + wn * (BN / 2) + nf * 16 + c] = acc[mf][nf][r];
        }
  }
}

// ---------------- flash attention (no mask), swapped-operand 32x32, KVB=128.
// 4 waves x 32 q-rows = QBLK 128. K AND V^T staged via swizzled global_load_lds
// (dbuf, prefetch-before-compute, 1 barrier/tile). Natural 2-D grid (R3-style;
// XCD-grouping measured -26% in R7 -- L3-fit regime, m160).
// K LDS:  [128 keys][128B], chunk s holds logical chunk s^(row&7).
// Vt LDS: [64 d][256B keys], chunk c holds logical key-chunk c^(d&15).
__global__ __launch_bounds__(256, 2) void attn_k(const __bf16* __restrict__ QK,
                                                 const __bf16* __restrict__ Vt,
                                                 __bf16* __restrict__ Yb) {
  constexpr int TT = 2048, KVB = 128, NT = TT / KVB;
  __shared__ __align__(16) char smem[65536];
  const int tid = threadIdx.x, lane = tid & 63, w = tid >> 6;
  const int q5 = lane & 31, h = lane >> 5;
  const int qb = blockIdx.x, bh = blockIdx.y;
  const int b = bh / 12, hd = bh % 12;
  const size_t ldq = 1536;
  const __bf16* Qg = QK + (size_t)(b * TT) * ldq + hd * 64;
  const __bf16* Kg = QK + (size_t)(b * TT) * ldq + 768 + hd * 64;
  const __bf16* Vtg = Vt + (size_t)(b * 12 + hd) * 64 * 2048;

  // Q fragment (B-operand): lane holds Q[qrow][16t + 8h .. +7]
  const int qrow = qb * 128 + w * 32 + q5;
  bf16x8 aq[4];
#pragma unroll
  for (int t = 0; t < 4; ++t)
    aq[t] = *(const bf16x8*)(Qg + (size_t)qrow * ldq + t * 16 + 8 * h);

  auto stageK = [&](int kv0, int buf) {
#pragma unroll
    for (int p = 0; p < 4; ++p) {
      int cid = p * 256 + tid;
      int row = cid >> 3, s = cid & 7;
      gload16(Kg + (size_t)(kv0 + row) * ldq + 8 * (s ^ (row & 7)),
              smem + buf * 16384 + cid * 16);
    }
  };
  auto stageVt = [&](int kv0, int buf) {
#pragma unroll
    for (int p = 0; p < 4; ++p) {
      int cid = p * 256 + tid;
      int row = cid >> 4, cc = cid & 15;
      gload16(Vtg + (size_t)row * 2048 + kv0 + 8 * (cc ^ (row & 15)),
              smem + 32768 + buf * 16384 + cid * 16);
    }
  };

  f32x16 Yacc[2] = {};  // Y^T[d][q=q5], d = (r&3)+8*(r>>2)+4h+32*dh
  const float SC = 0.18033688f;  // 0.125 * log2(e)  (softmax in exp2 domain)
  float m2 = -__builtin_inff(), l_run = 0.f;

  stageK(0, 0);
  stageVt(0, 0);
  __syncthreads();

  f32x16 Sv[4];
#define SV(i) Sv[(i) >> 4][(i) & 15]

  for (int t = 0; t < NT; ++t) {
    const int cur = t & 1;
    const char* Kb = smem + cur * 16384;
    const char* Vb = smem + 32768 + cur * 16384;
    if (t + 1 < NT) {
      stageK((t + 1) * KVB, cur ^ 1);
      stageVt((t + 1) * KVB, cur ^ 1);
    }

    // ---- S^T = mfma(A=K, B=Q): lane owns q=q5; 64 scores
#pragma unroll
    for (int j = 0; j < 4; ++j) {
      f32x16 S = {};
#pragma unroll
      for (int tt = 0; tt < 4; ++tt) {
        int row = j * 32 + q5;
        int chunk = (2 * tt + h) ^ (q5 & 7);
        bf16x8 kf = *(const bf16x8*)(Kb + row * 128 + 16 * chunk);
        S = __builtin_amdgcn_mfma_f32_32x32x16_bf16(kf, aq[tt], S, 0, 0, 0);
      }
      Sv[j] = S;
    }

    // ---- online softmax (exp2 domain); 4-chain trees, defer-max rescale
    float m0 = SV(0), m1 = SV(1), m2c = SV(2), m3 = SV(3);
#pragma unroll
    for (int i = 4; i < 64; i += 4) {
      m0 = fmaxf(m0, SV(i));       m1 = fmaxf(m1, SV(i + 1));
      m2c = fmaxf(m2c, SV(i + 2)); m3 = fmaxf(m3, SV(i + 3));
    }
    float mx = fmaxf(fmaxf(m0, m1), fmaxf(m2c, m3));
    mx = fmaxf(mx, __shfl_xor(mx, 32));
    mx *= SC;
    if (!__all(mx <= m2 + 8.0f)) {  // defer rescale while P <= 2^8
      float mn = fmaxf(m2, mx);
      float corr = __builtin_exp2f(m2 - mn);
      l_run *= corr;
#pragma unroll
      for (int dh = 0; dh < 2; ++dh)
#pragma unroll
        for (int r = 0; r < 16; ++r) Yacc[dh][r] *= corr;
      m2 = mn;
    }
    float rs0 = 0.f, rs1 = 0.f, rs2 = 0.f, rs3 = 0.f;
#pragma unroll
    for (int i = 0; i < 64; i += 4) {
      float e0 = __builtin_exp2f(fmaf(SV(i), SC, -m2));
      float e1 = __builtin_exp2f(fmaf(SV(i + 1), SC, -m2));
      float e2 = __builtin_exp2f(fmaf(SV(i + 2), SC, -m2));
      float e3 = __builtin_exp2f(fmaf(SV(i + 3), SC, -m2));
      SV(i) = e0; SV(i + 1) = e1; SV(i + 2) = e2; SV(i + 3) = e3;
      rs0 += e0; rs1 += e1; rs2 += e2; rs3 += e3;
    }
    float rs = (rs0 + rs1) + (rs2 + rs3);
    rs += __shfl_xor(rs, 32);
    l_run += rs;

    // ---- Y^T += mfma(A=V^T from swizzled LDS, B=P^T) per 16-key sub-tile
#pragma unroll
    for (int j = 0; j < 4; ++j) {
#pragma unroll
      for (int s = 0; s < 2; ++s) {
        int e0 = j * 16 + s * 8;
        uint32_t pk01 = pack2(SV(e0 + 0), SV(e0 + 1));
        uint32_t pk23 = pack2(SV(e0 + 2), SV(e0 + 3));
        uint32_t pk45 = pack2(SV(e0 + 4), SV(e0 + 5));
        uint32_t pk67 = pack2(SV(e0 + 6), SV(e0 + 7));
        uint32_t fa = (uint32_t)__shfl_xor((int)(h ? pk01 : pk45), 32);
        uint32_t fb = (uint32_t)__shfl_xor((int)(h ? pk23 : pk67), 32);
        u32x4 pw;
        pw[0] = h ? fa : pk01;
        pw[1] = h ? fb : pk23;
        pw[2] = h ? pk45 : fa;
        pw[3] = h ? pk67 : fb;
        bf16x8 pfrag = __builtin_bit_cast(bf16x8, pw);
        int lc = j * 4 + s * 2 + h;  // logical 8-key chunk index
#pragma unroll
        for (int dh = 0; dh < 2; ++dh) {
          int byte = (dh * 32 + q5) * 256 + 16 * (lc ^ (q5 & 15));
          bf16x8 vf = *(const bf16x8*)(Vb + byte);
          Yacc[dh] = __builtin_amdgcn_mfma_f32_32x32x16_bf16(vf, pfrag, Yacc[dh], 0, 0, 0);
        }
      }
    }
    __syncthreads();
  }
#undef SV

  // ---- epilogue: scale by 1/l, transpose via LDS (reuse smem), coalesced stores
  float rl = __builtin_amdgcn_rcpf(l_run);
  char* yb = smem + w * (32 * 144);  // per-wave [32 q][72 bf16] region (144B rows)
#pragma unroll
  for (int dh = 0; dh < 2; ++dh)
#pragma unroll
    for (int a = 0; a < 4; ++a) {
      bf16x4 pkv;
#pragma unroll
      for (int i = 0; i < 4; ++i) pkv[i] = (__bf16)(Yacc[dh][a * 4 + i] * rl);
      int d0 = a * 8 + 4 * h + 32 * dh;
      *(bf16x4*)(yb + q5 * 144 + d0 * 2) = pkv;
    }
  __bf16* Yrow = Yb + (size_t)(b * TT + qb * 128 + w * 32) * 768 + hd * 64;
#pragma unroll
  for (int k = 0; k < 4; ++k) {
    int chunk = k * 64 + lane;
    int qr = chunk >> 3, sr = chunk & 7;
    bf16x8 vv = *(const bf16x8*)(yb + qr * 144 + sr * 16);
    *(bf16x8*)(Yrow + (size_t)qr * 768 + sr * 8) = vv;
  }
}

extern "C" void kernel_launch(void* const* d_in, const int* in_sizes, int n_in,
                              void* d_out, int out_size, void* d_ws, size_t ws_size,
                              hipStream_t stream) {
  const float* x = (const float*)d_in[0];
  const float* cosT = (const float*)d_in[1];
  const float* sinT = (const float*)d_in[2];
  const float* wq = (const float*)d_in[3];
  const float* wk = (const float*)d_in[4];
  const float* wv = (const float*)d_in[5];
  const float* wp = (const float*)d_in[6];

  char* ws = (char*)d_ws;
  __bf16* xb  = (__bf16*)(ws);                 //  6,291,456 B  (4096x768 bf16)
  __bf16* WT  = (__bf16*)(ws + 6291456);       //  4,718,592 B  (3072x768 bf16)
  __bf16* QKb = (__bf16*)(ws + 11010048);      // 12,582,912 B  (4096x1536 bf16)
  __bf16* Vt  = (__bf16*)(ws + 23592960);      //  6,291,456 B  (24x64x2048 bf16)
  __bf16* Yb  = (__bf16*)(ws + 29884416);      //  6,291,456 B  (4096x768 bf16)

  prep_k<<<3072, 256, 0, stream>>>(x, wq, wk, wv, wp, xb, WT);
  // fused QKV gemm: M=4096, N=2304, K=768; Q,K -> QKb (ldc=1536), V -> Vt transposed
  gemm_k<1, 128><<<576, 256, 0, stream>>>(xb, WT, (void*)QKb, Vt, cosT, sinT,
                                          768, 768, 768, 1536, 576, 18);
  // attn: natural 2-D grid (16 qb x 24 bh)
  attn_k<<<dim3(16, 24), 256, 0, stream>>>(QKb, Vt, Yb);
  // proj gemm: M=4096, N=768, K=768, 128x64 tiles -> 384 blocks
  gemm_k<0, 64><<<384, 256, 0, stream>>>(Yb, WT + (size_t)2304 * 768, d_out, nullptr,
                                         nullptr, nullptr, 768, 768, 768, 768, 384, 12);
}